// Round 8
// baseline (299.395 us; speedup 1.0000x reference)
//
#include <hip/hip_runtime.h>
#include <stdint.h>
#include <stddef.h>

#define Bb 128
#define Nn 512
#define Hh 128
#define ROWS (Bb*Nn)

typedef __bf16 bf16;
typedef __bf16 bf16x2 __attribute__((ext_vector_type(2)));
typedef __bf16 bf16x4 __attribute__((ext_vector_type(4)));
typedef __bf16 bf16x8 __attribute__((ext_vector_type(8)));
typedef float  f32x4  __attribute__((ext_vector_type(4)));

__device__ __forceinline__ void glds16(const void* g, void* l) {
  __builtin_amdgcn_global_load_lds(
      (const __attribute__((address_space(1))) void*)g,
      (__attribute__((address_space(3))) void*)l, 16, 0, 0);
}

// -------------------------------------------------- weight prep (all in one)
// fp32 W[k][c] -> bf16 W^T[c][k ^ ((c&7)<<3)]  (swizzle pre-applied)
__global__ __launch_bounds__(256) void prep_all(
    const float* __restrict__ eW1, const float* __restrict__ Wm,
    const float* __restrict__ Wu, bf16* __restrict__ WTe,
    bf16* __restrict__ WTm, bf16* __restrict__ WTu) {
  int idx = blockIdx.x*256 + threadIdx.x;
  if (idx < 16384) {                       // eW1: 128x128
    int k = idx >> 7, c = idx & 127;
    WTe[c*128 + (k ^ ((c & 7) << 3))] = (bf16)eW1[idx];
  } else if (idx < 16384 + 49152) {        // Wm: 3x128x128
    int sub = idx - 16384;
    int m = sub >> 14, r = sub & 16383;
    int k = r >> 7, c = r & 127;
    WTm[m*16384 + c*128 + (k ^ ((c & 7) << 3))] = (bf16)Wm[sub];
  } else if (idx < 16384 + 49152 + 98304) { // Wu: 3x256x128
    int sub = idx - 65536;
    int m = sub >> 15, r = sub & 32767;
    int k = r >> 7, c = r & 127;
    WTu[m*32768 + c*256 + (k ^ ((c & 7) << 3))] = (bf16)Wu[sub];
  }
}

// -------------------------------------------------- fused embed L1+L2+msg0
// h = relu(relu(jets@W0+b0)@W1+b1); msgT0 = relu(h@Wm0+bm0)^T. 128 rows/block.
__global__ __launch_bounds__(256) void embed_msg0(
    const float* __restrict__ jets, const float* __restrict__ W0,
    const float* __restrict__ b0, const bf16* __restrict__ WTe,
    const float* __restrict__ b1, const bf16* __restrict__ WTm0,
    const float* __restrict__ bm0, bf16* __restrict__ h,
    bf16* __restrict__ msgT) {
  __shared__ float sW0[8*128];
  __shared__ float sb0[128];
  __shared__ bf16 h0s[128*128];   // swizzled; reused for h-tile later
  __shared__ bf16 sWT[128*128];   // swizzled W1^T
  const int t = threadIdx.x;
  const int w = t >> 6, lane = t & 63, l15 = lane & 15, g = lane >> 4;
  const int row_blk = blockIdx.x*128;
  for (int q = w; q < 32; q += 4)
    glds16((const char*)WTe + q*1024 + lane*16, (char*)(void*)sWT + q*1024);
  for (int i = t; i < 8*128; i += 256) sW0[i] = W0[i];
  if (t < 128) sb0[t] = b0[t];
  __syncthreads();
  // layer 1: thread owns 1 row, 64 cols
  {
    const int row = t & 127, colbase = (t >> 7) * 64;
    const float4* jp = (const float4*)(jets + ((size_t)row_blk + row)*8);
    float4 x0 = jp[0], x1 = jp[1];
    float x[8] = {x0.x,x0.y,x0.z,x0.w,x1.x,x1.y,x1.z,x1.w};
    const int sw = (row & 7) << 3;
#pragma unroll
    for (int cg = 0; cg < 16; ++cg) {
      int c0 = colbase + cg*4;
      bf16x4 o;
#pragma unroll
      for (int j = 0; j < 4; ++j) {
        float a = sb0[c0+j];
#pragma unroll
        for (int f = 0; f < 8; ++f) a = fmaf(x[f], sW0[f*128 + c0 + j], a);
        o[j] = (bf16)fmaxf(a, 0.f);
      }
      *(bf16x4*)(h0s + row*128 + (c0 ^ sw)) = o;
    }
  }
  __syncthreads();
  // layer 2: MFMA, 4 waves 2x2
  const int wr = (w & 1)*64, wc = (w >> 1)*64;
  f32x4 acc[4][4];
#pragma unroll
  for (int m = 0; m < 4; ++m)
#pragma unroll
    for (int n = 0; n < 4; ++n) acc[m][n] = (f32x4){0.f,0.f,0.f,0.f};
#pragma unroll
  for (int kk = 0; kk < 128; kk += 32) {
    bf16x8 bfr[4], wfr[4];
#pragma unroll
    for (int n = 0; n < 4; ++n) {
      int row = wr + n*16 + l15;
      bfr[n] = *(const bf16x8*)(h0s + row*128 + ((kk + 8*g) ^ ((row & 7) << 3)));
    }
#pragma unroll
    for (int m = 0; m < 4; ++m) {
      int c = wc + m*16 + l15;
      wfr[m] = *(const bf16x8*)(sWT + c*128 + ((kk + 8*g) ^ ((c & 7) << 3)));
    }
#pragma unroll
    for (int m = 0; m < 4; ++m)
#pragma unroll
      for (int n = 0; n < 4; ++n)
        acc[m][n] = __builtin_amdgcn_mfma_f32_16x16x32_bf16(wfr[m], bfr[n], acc[m][n], 0,0,0);
  }
  __syncthreads();   // everyone done reading h0s before overwrite
#pragma unroll
  for (int m = 0; m < 4; ++m) {
    f32x4 bs = *(const f32x4*)(b1 + wc + m*16 + g*4);
#pragma unroll
    for (int n = 0; n < 4; ++n) {
      int lr = wr + n*16 + l15;
      int r = row_blk + lr;
      int c0 = wc + m*16 + g*4;
      bf16x4 o;
#pragma unroll
      for (int j = 0; j < 4; ++j) o[j] = (bf16)fmaxf(acc[m][n][j] + bs[j], 0.f);
      *(bf16x4*)(h + (size_t)r*128 + c0) = o;
      *(bf16x4*)(h0s + lr*128 + (c0 ^ ((lr & 7) << 3))) = o;
    }
  }
  __syncthreads();
  // msg0: msgT = relu(htile @ Wm0 + bm0), TRANSOUT; Wm0 frags from global(L2)
  {
    f32x4 acc2[4][4];
#pragma unroll
    for (int m = 0; m < 4; ++m)
#pragma unroll
      for (int n = 0; n < 4; ++n) acc2[m][n] = (f32x4){0.f,0.f,0.f,0.f};
#pragma unroll
    for (int kk = 0; kk < 128; kk += 32) {
      bf16x8 bfr[4], wfr[4];
#pragma unroll
      for (int n = 0; n < 4; ++n) {
        int lr = wr + n*16 + l15;
        bfr[n] = *(const bf16x8*)(h0s + lr*128 + ((kk + 8*g) ^ ((lr & 7) << 3)));
      }
#pragma unroll
      for (int m = 0; m < 4; ++m) {
        int c = wc + m*16 + l15;
        wfr[m] = *(const bf16x8*)(WTm0 + c*128 + ((kk + 8*g) ^ ((c & 7) << 3)));
      }
#pragma unroll
      for (int m = 0; m < 4; ++m)
#pragma unroll
        for (int n = 0; n < 4; ++n)
          acc2[m][n] = __builtin_amdgcn_mfma_f32_16x16x32_bf16(bfr[n], wfr[m], acc2[m][n], 0,0,0);
    }
    const int b = row_blk >> 9;
    const int rbase = (row_blk & 511) + wr;
#pragma unroll
    for (int m = 0; m < 4; ++m) {
      int c = wc + m*16 + l15;
      float bc = bm0[c];
#pragma unroll
      for (int n = 0; n < 4; ++n) {
        int rl = rbase + n*16 + g*4;
        bf16x4 o;
#pragma unroll
        for (int j = 0; j < 4; ++j) o[j] = (bf16)fmaxf(acc2[m][n][j] + bc, 0.f);
        *(bf16x4*)(msgT + ((size_t)(b*128 + c))*512 + rl) = o;
      }
    }
  }
}

// -------------------------------------------------- fused per-iteration kernel
// 64-row blocks (grid 1024), wave owns 16 rows -> all B/C-phase accesses are
// wave-private (only 2 barriers). LDS 36KB -> 4 blocks/CU for latency hiding.
// Phase A: agg tile (LDS, swizzled). Phase B: h_new = relu([h|agg]@Wu+bu)*mask
// (in-place, own rows). Phase C (DO_MSG): msgTout = relu(h_new@Wm+bm)^T.
// msgTin != msgTout (ping-pong; cross-block WAR otherwise).
// Block = (batch b = wgid&127 [XCD-pinned], 64-row chunk ic = wgid>>7).
template<bool COMPUTE_L, bool DO_MSG>
__global__ __launch_bounds__(256) void iter_fused(
    const float* __restrict__ jets, const float* __restrict__ mask,
    float* __restrict__ rsum, const bf16* __restrict__ msgTin,
    bf16* __restrict__ h,
    const bf16* __restrict__ WTu, const float* __restrict__ bu,
    const bf16* __restrict__ WTm, const float* __restrict__ bm,
    bf16* __restrict__ msgTout) {
  __shared__ __align__(16) char smem[36864];
  float* Xs    = (float*)smem;                // [512*9]  18KB (phase A)
  float* cbs   = (float*)(smem + 18432);      // [512]     2KB (phase A)
  bf16*  htile = (bf16*)smem;                 // [64][128] 16KB (phase B/C)
  bf16*  aggs  = (bf16*)(smem + 20480);       // [64][128] 16KB
  const int t = threadIdx.x;
  const int b  = blockIdx.x & 127;
  const int ic = blockIdx.x >> 7;             // 0..7
  const int i0 = ic*64;
  const int w = t >> 6, lane = t & 63, l15 = lane & 15, g = lane >> 4;
  const int lr = w*16 + l15;                  // wave-private local row 0..63

  // ---- stage Xs / cbs
  const float* jb = jets + (size_t)b*Nn*8;
  for (int j = t; j < Nn; j += 256) {
    float s2 = 0.f;
#pragma unroll
    for (int f = 0; f < 8; ++f) { float v = jb[j*8+f]; Xs[j*9+f] = v; s2 = fmaf(v,v,s2); }
    cbs[j] = s2 + (mask[(size_t)b*Nn+j] > 0.f ? 0.f : 1e9f);
  }
  __syncthreads();

  // ================= Phase A: agg row i = i0 + lr (16 rows/wave)
  {
    const int i = i0 + lr;
    float xi2[8], sq = 0.f;
#pragma unroll
    for (int f = 0; f < 8; ++f) {
      float v = Xs[i*9+f];
      xi2[f] = 2.f*v;
      sq = fmaf(v, v, sq);
    }
    float r_i, lsum = 0.f;
    if (!COMPUTE_L) r_i = rsum[(size_t)b*Nn+i];
    f32x4 acc[8];
#pragma unroll
    for (int m = 0; m < 8; ++m) acc[m] = (f32x4){0.f,0.f,0.f,0.f};
    const bf16* mB = msgTin + (size_t)b*128*512;
#pragma unroll 2
    for (int j0 = 0; j0 < Nn; j0 += 32) {
      bf16x8 afr[8];
#pragma unroll
      for (int m = 0; m < 8; ++m)
        afr[m] = *(const bf16x8*)(mB + (size_t)(m*16 + l15)*512 + j0 + 8*g);
      bf16x8 pfr;
#pragma unroll
      for (int e = 0; e < 8; ++e) {
        int j = j0 + 8*g + e;
        float d = -(cbs[j] + sq);
#pragma unroll
        for (int f = 0; f < 8; ++f) d = fmaf(xi2[f], Xs[j*9+f], d);
        float ev = __expf(d);
        if (COMPUTE_L) lsum += ev;
        pfr[e] = (bf16)ev;
      }
#pragma unroll
      for (int m = 0; m < 8; ++m)
        acc[m] = __builtin_amdgcn_mfma_f32_16x16x32_bf16(afr[m], pfr, acc[m], 0,0,0);
    }
    if (COMPUTE_L) {
      float s = lsum;
      s += __shfl_xor(s, 16, 64);
      s += __shfl_xor(s, 32, 64);
      r_i = 1.f/s;
      if (g == 0) rsum[(size_t)b*Nn + i] = r_i;
    }
    // epilogue -> aggs LDS (swizzled), wave-private rows
#pragma unroll
    for (int m = 0; m < 8; ++m) {
      bf16x4 o;
#pragma unroll
      for (int j = 0; j < 4; ++j) o[j] = (bf16)(acc[m][j] * r_i);
      int c0 = m*16 + g*4;
      *(bf16x4*)(aggs + lr*128 + (c0 ^ ((lr & 7) << 3))) = o;
    }
  }
  __syncthreads();   // Xs dead (htile may overwrite); aggs rows are wave-private

  // ================= Phase B: h_new = relu([h|agg] @ Wu + bu) * mask
  const size_t grow = (size_t)b*Nn + i0 + lr;   // this lane's global row
  {
    f32x4 acc[8];
#pragma unroll
    for (int m = 0; m < 8; ++m) acc[m] = (f32x4){0.f,0.f,0.f,0.f};
#pragma unroll
    for (int kk = 0; kk < 256; kk += 32) {
      bf16x8 bfr;
      if (kk < 128) {
        bfr = *(const bf16x8*)(h + grow*128 + kk + 8*g);
      } else {
        int kl = (kk - 128) + 8*g;
        bfr = *(const bf16x8*)(aggs + lr*128 + (kl ^ ((lr & 7) << 3)));
      }
      bf16x8 wfr[8];
#pragma unroll
      for (int m = 0; m < 8; ++m) {
        int c = m*16 + l15;
        wfr[m] = *(const bf16x8*)(WTu + c*256 + ((kk + 8*g) ^ ((c & 7) << 3)));
      }
#pragma unroll
      for (int m = 0; m < 8; ++m)
        acc[m] = __builtin_amdgcn_mfma_f32_16x16x32_bf16(wfr[m], bfr, acc[m], 0,0,0);
    }
    // epilogue: wave-private rows -> no barrier needed
    float mv = mask[grow];
#pragma unroll
    for (int m = 0; m < 8; ++m) {
      int c0 = m*16 + g*4;
      f32x4 bs = *(const f32x4*)(bu + c0);
      bf16x4 o;
#pragma unroll
      for (int j = 0; j < 4; ++j)
        o[j] = (bf16)(fmaxf(acc[m][j] + bs[j], 0.f) * mv);
      *(bf16x4*)(h + grow*128 + c0) = o;
      if (DO_MSG)
        *(bf16x4*)(htile + lr*128 + (c0 ^ ((lr & 7) << 3))) = o;
    }
  }
  if (!DO_MSG) return;

  // ================= Phase C: msgTout = relu(h_new @ Wm + bm)^T (wave-private)
  {
    f32x4 acc[8];
#pragma unroll
    for (int m = 0; m < 8; ++m) acc[m] = (f32x4){0.f,0.f,0.f,0.f};
#pragma unroll
    for (int kk = 0; kk < 128; kk += 32) {
      bf16x8 bfr = *(const bf16x8*)(htile + lr*128 + ((kk + 8*g) ^ ((lr & 7) << 3)));
      bf16x8 wfr[8];
#pragma unroll
      for (int m = 0; m < 8; ++m) {
        int c = m*16 + l15;
        wfr[m] = *(const bf16x8*)(WTm + c*128 + ((kk + 8*g) ^ ((c & 7) << 3)));
      }
#pragma unroll
      for (int m = 0; m < 8; ++m)
        acc[m] = __builtin_amdgcn_mfma_f32_16x16x32_bf16(bfr, wfr[m], acc[m], 0,0,0);
    }
    const int rl = i0 + w*16 + g*4;
#pragma unroll
    for (int m = 0; m < 8; ++m) {
      int c = m*16 + l15;
      float bc = bm[c];
      bf16x4 o;
#pragma unroll
      for (int j = 0; j < 4; ++j) o[j] = (bf16)fmaxf(acc[m][j] + bc, 0.f);
      *(bf16x4*)(msgTout + ((size_t)(b*128 + c))*512 + rl) = o;
    }
  }
}

// -------------------------------------------------- fused pool + readout
__global__ __launch_bounds__(256) void pool_readout(
    const bf16* __restrict__ h, const float* __restrict__ mask,
    const float* __restrict__ W1, const float* __restrict__ b1,
    const float* __restrict__ W2, const float* __restrict__ b2,
    float* __restrict__ out) {
  __shared__ float part[3][128];
  __shared__ float pl[128];
  __shared__ float hid[128];
  int b = blockIdx.x, t = threadIdx.x, g = t >> 6, cp = (t & 63)*2;
  float a0 = 0.f, a1 = 0.f;
  for (int n = g*128; n < g*128+128; ++n) {
    float mv = mask[(size_t)b*Nn + n];
    bf16x2 v = *(const bf16x2*)(h + ((size_t)b*Nn + n)*128 + cp);
    a0 = fmaf((float)v[0], mv, a0);
    a1 = fmaf((float)v[1], mv, a1);
  }
  if (g > 0) { part[g-1][cp] = a0; part[g-1][cp+1] = a1; }
  __syncthreads();
  if (g == 0) {
    pl[cp]   = a0 + part[0][cp]   + part[1][cp]   + part[2][cp];
    pl[cp+1] = a1 + part[0][cp+1] + part[1][cp+1] + part[2][cp+1];
  }
  __syncthreads();
  if (t < 128) {
    float a = b1[t];
#pragma unroll 4
    for (int j = 0; j < 128; ++j) a = fmaf(pl[j], W1[j*128 + t], a);
    hid[t] = fmaxf(a, 0.f);
  }
  __syncthreads();
  if (t < 128) {
    float a = b2[t];
#pragma unroll 4
    for (int j = 0; j < 128; ++j) a = fmaf(hid[j], W2[j*128 + t], a);
    out[(size_t)b*128 + t] = a;
  }
}

// -------------------------------------------------- launch
extern "C" void kernel_launch(void* const* d_in, const int* in_sizes, int n_in,
                              void* d_out, int out_size, void* d_ws, size_t ws_size,
                              hipStream_t stream) {
  const float* jets = (const float*)d_in[0];
  const float* mask = (const float*)d_in[1];
  const float* eW0  = (const float*)d_in[2];
  const float* eb0  = (const float*)d_in[3];
  const float* eW1  = (const float*)d_in[4];
  const float* eb1  = (const float*)d_in[5];
  const float* Wm   = (const float*)d_in[6];
  const float* bm   = (const float*)d_in[7];
  const float* Wu   = (const float*)d_in[8];
  const float* bu   = (const float*)d_in[9];
  const float* rW1  = (const float*)d_in[10];
  const float* rb1  = (const float*)d_in[11];
  const float* rW2  = (const float*)d_in[12];
  const float* rb2  = (const float*)d_in[13];
  float* out = (float*)d_out;

  bf16* h     = (bf16*)d_ws;                    // ROWS*128
  bf16* msgTA = h     + (size_t)ROWS*128;       // ROWS*128 (layout [b][c][n])
  bf16* msgTB = msgTA + (size_t)ROWS*128;       // ROWS*128 (ping-pong)
  bf16* WTe   = msgTB + (size_t)ROWS*128;       // 128*128
  bf16* WTm   = WTe   + 128*128;                // 3*128*128
  bf16* WTu   = WTm   + 3*128*128;              // 3*256*128
  float* rsum = (float*)(WTu + 3*256*128);      // ROWS (1/l_i)

  prep_all<<<640, 256, 0, stream>>>(eW1, Wm, Wu, WTe, WTm, WTu);
  embed_msg0<<<ROWS/128, 256, 0, stream>>>(jets, eW0, eb0, WTe, eb1,
                                           WTm, bm, h, msgTA);
  // iter 0 (computes 1/l_i on the fly): msgTA -> msgTB
  iter_fused<true,true><<<Bb*8, 256, 0, stream>>>(
      jets, mask, rsum, msgTA, h,
      WTu, bu, WTm + (size_t)1*128*128, bm + 1*128, msgTB);
  // iter 1: msgTB -> msgTA
  iter_fused<false,true><<<Bb*8, 256, 0, stream>>>(
      jets, mask, rsum, msgTB, h,
      WTu + (size_t)1*256*128, bu + 1*128,
      WTm + (size_t)2*128*128, bm + 2*128, msgTA);
  // iter 2 (no next msg): reads msgTA
  iter_fused<false,false><<<Bb*8, 256, 0, stream>>>(
      jets, mask, rsum, msgTA, h,
      WTu + (size_t)2*256*128, bu + 2*128, nullptr, nullptr, nullptr);

  pool_readout<<<Bb, 256, 0, stream>>>(h, mask, rW1, rb1, rW2, rb2, out);
}